// Round 7
// baseline (79.760 us; speedup 1.0000x reference)
//
#include <hip/hip_runtime.h>
#include <math.h>

// Tiny_ConvCIFAR10_KAN_Discriminator — per-PIXEL formulation, single fused
// kernel; every block rebuilds the 12 KB class-summed table with a LEAN build
// that overlaps the image HBM stream (loads issued first).
//
// out[b] = sigmoid( (1/256) * [ corr + sum_{real pixels p} Q_{c,rc(r),cc(col)}(v_p) ] + lb )
//
// After folding lin_w into the weights, the result is a plain sum of P_f(v) over
// all (position, feature) pairs; P_f is piecewise-quadratic in v (quadratic
// B-spline on uniform knots; half-interval i2 = clamp(floor(3v+7)+1, 0, 15);
// ReLU*base folded into beta for x>=0 rows; i2=15 row = bwc*x exactly, i2=0 row
// = 0 — both fall out of the masked S reads). A pixel at (r,col) occurs at a
// class-determined set of (kh,kw) offsets (row class: r==0 ->{1}, even interior
// ->{1,3}, odd interior ->{0,2}, r==31 ->{2}; columns identical); the sum of
// those quadratics is ONE quadratic -> one float4 table row per pixel. Zero-pad
// pixels contribute corr = sum_f N_f * alpha_{f,i2=8}, folded into the reduce.
//
// __launch_bounds__(256, 6): ~85-VGPR cap. (256,8) would cap at 64 and risks
// spilling px0..px2 (live across the whole build as an HBM prefetch) to
// scratch — a ~50 MB traffic catastrophe. 6 blocks/CU = 24 waves/CU is ample
// TLP for a ~50%-of-HBM-roofline kernel.

__global__ __launch_bounds__(256, 6) void kan_fused(
    const float* __restrict__ x,    // [B][3][32][32]
    const float* __restrict__ bw,   // [8][48]
    const float* __restrict__ sw,   // [8][48][5]
    const float* __restrict__ lw,   // [8]
    const float* __restrict__ lb,   // [1]
    float* __restrict__ out)        // [B]
{
  __shared__ float  S[240];      // folded spline weights [f][5]
  __shared__ float  bwc[48];     // folded base weights
  __shared__ float4 T[768];      // [(c*4+rc)*4+ccl][16] class-summed quadratics
  __shared__ float  red[4];

  const int tid = threadIdx.x;
  const int b = blockIdx.x;

  // ---- image loads first: in flight across the entire table build ----
  const float4* xg = reinterpret_cast<const float4*>(x) + (size_t)b * 768;
  float4 px0 = xg[tid];
  float4 px1 = xg[tid + 256];
  float4 px2 = xg[tid + 512];

  // ---- fold lin_w into weights (lw uniform -> scalar regs; coalesced sw/bw) ----
  float l[8];
  #pragma unroll
  for (int o = 0; o < 8; ++o) l[o] = lw[o];

  if (tid < 240) {
    float v = 0.f;
    #pragma unroll
    for (int o = 0; o < 8; ++o) v = fmaf(l[o], sw[o * 240 + tid], v);
    S[tid] = v;
  }
  if (tid < 48) {
    float v = 0.f;
    #pragma unroll
    for (int o = 0; o < 8; ++o) v = fmaf(l[o], bw[o * 48 + tid], v);
    bwc[tid] = v;
  }
  __syncthreads();

  // ---- inline P-eval: piecewise quadratic (alpha,beta,gamma) for (f, i2) ----
  auto peval = [&](int f, int i2, float& pa, float& pb, float& pc) {
    int j2 = i2 - 1;
    int j  = j2 >> 1;                 // i2=0 -> j=-1 -> all reads masked -> zeros
    float d = 3.5f - (float)j;
    int k0 = j - 2, k1 = j - 1, k2 = j;
    int c0 = min(max(k0, 0), 4), c1 = min(max(k1, 0), 4), c2 = min(max(k2, 0), 4);
    float s0 = S[f * 5 + c0]; s0 = (k0 == c0) ? s0 : 0.f;
    float s1 = S[f * 5 + c1]; s1 = (k1 == c1) ? s1 : 0.f;
    float s2 = S[f * 5 + c2]; s2 = (k2 == c2) ? s2 : 0.f;
    float A = 0.5f * (s0 + s1);       // t-poly: A + B t + C t^2, t = 1.5x + d
    float B = s1 - s0;
    float C = 0.5f * s0 - s1 + 0.5f * s2;
    pa = A + d * (B + d * C);                                  // alpha
    pb = 1.5f * B + 3.f * d * C + (j2 >= 7 ? bwc[f] : 0.f);    // beta (+ReLU fold)
    pc = 2.25f * C;                                            // gamma
  };

  // ---- build class-summed table T directly (P recomputed inline, no P array) ----
  #pragma unroll
  for (int k = 0; k < 3; ++k) {
    int e = tid + (k << 8);
    int i2 = e & 15, g = e >> 4;
    int ccl = g & 3, rc = (g >> 2) & 3, c = g >> 4;
    int khA = (0x2011 >> (rc * 4)) & 15;   // {rc0:1, rc1:1, rc2:0, rc3:2}
    int kwA = (0x2011 >> (ccl * 4)) & 15;
    bool hB = !(rc & 1);                   // second kh (=khA+2) present
    bool wB = !(ccl & 1);                  // second kw (=kwA+2) present
    int fA = (c * 4 + khA) * 4 + kwA;
    float ax, bx, cx, ta, tb, tc;
    peval(fA, i2, ax, bx, cx);
    if (wB)       { peval(fA + 2,  i2, ta, tb, tc); ax += ta; bx += tb; cx += tc; }
    if (hB)       { peval(fA + 8,  i2, ta, tb, tc); ax += ta; bx += tb; cx += tc; }
    if (hB && wB) { peval(fA + 10, i2, ta, tb, tc); ax += ta; bx += tb; cx += tc; }
    T[e] = make_float4(ax, bx, cx, 0.f);
  }

  // ---- pad-pixel correction, parallel across 48 lanes, folded into reduce ----
  float s = 0.f;
  if (tid < 48) {
    float pa, pb, pc;
    peval(tid, 8, pa, pb, pc);                 // P_f(0) = alpha at i2=8
    int kh = (tid >> 2) & 3, kw = tid & 3;
    int eh = (kh == 0 || kh == 3) ? 1 : 0;
    int ew = (kw == 0 || kw == 3) ? 1 : 0;
    s = (float)(16 * eh + 16 * ew - (eh & ew)) * pa;
  }
  __syncthreads();

  // ---- main: 12 pixels, one table row each ----
  auto acc1 = [&](float v, int fb) {
    float fj = floorf(fmaf(v, 3.f, 7.f));      // half-interval j2
    fj = fminf(fmaxf(fj, -1.f), 14.f);         // clamp rows handle tails exactly
    int i2 = (int)fj + 1;
    float4 co = T[fb + i2];
    s = fmaf(v, fmaf(v, co.z, co.y), s + co.x);
  };
  const float4 pxa[3] = {px0, px1, px2};
  #pragma unroll
  for (int i = 0; i < 3; ++i) {
    int i4 = tid + (i << 8);
    int flat = i4 << 2;
    int c = flat >> 10;
    int rem = flat & 1023;
    int r = rem >> 5;
    int col0 = rem & 31;                        // 4-aligned column of px.x
    int rc = ((r & 1) << 1) + (r == 0 ? 1 : 0) + (r == 31 ? 1 : 0);
    int base = (((c << 2) | rc) << 6);          // ((c*4+rc)*4)*16 float4 rows
    acc1(pxa[i].x, base + ((col0 == 0) ? 16 : 0));   // col even: ccl 0 / edge 1
    acc1(pxa[i].y, base + 32);                        // col odd interior: ccl 2
    acc1(pxa[i].z, base);                             // col even interior: ccl 0
    acc1(pxa[i].w, base + ((col0 == 28) ? 48 : 32));  // col odd / col==31: ccl 2/3
  }

  // ---- block reduce (4 waves), mean, sigmoid ----
  #pragma unroll
  for (int off = 32; off; off >>= 1) s += __shfl_down(s, off);
  if ((tid & 63) == 0) red[tid >> 6] = s;
  __syncthreads();
  if (tid == 0) {
    float tot = (red[0] + red[1]) + (red[2] + red[3]);
    float z = tot * (1.f / 256.f) + lb[0];
    out[b] = 1.f / (1.f + expf(-z));
  }
}

extern "C" void kernel_launch(void* const* d_in, const int* in_sizes, int n_in,
                              void* d_out, int out_size, void* d_ws, size_t ws_size,
                              hipStream_t stream) {
  const float* x  = (const float*)d_in[0];
  const float* bw = (const float*)d_in[1];
  const float* sw = (const float*)d_in[2];
  const float* lw = (const float*)d_in[3];
  const float* lb = (const float*)d_in[4];
  float* out = (float*)d_out;
  int B = in_sizes[0] / 3072;   // 2048
  kan_fused<<<B, 256, 0, stream>>>(x, bw, sw, lw, lb, out);
}